// Round 6
// baseline (972.106 us; speedup 1.0000x reference)
//
#include <hip/hip_runtime.h>
#include <math.h>

#define N_RES 8192
#define N_IN  256
#define BATCH 16

// ---------------------------------------------------------------------------
// init: coalesced reads. state_T[r*16+b] = state[b*8192+r]; z_acc = bias bcast
// ---------------------------------------------------------------------------
__global__ void init_kernel(const float* __restrict__ state,
                            const float* __restrict__ x,
                            const float* __restrict__ bias,
                            float* __restrict__ z_acc,
                            float* __restrict__ state_T,
                            float* __restrict__ x_T) {
    int i = blockIdx.x * blockDim.x + threadIdx.x;
    if (i < N_RES * BATCH) {
        int r = i & (N_RES - 1);          // r fastest -> state read coalesced
        int b = i >> 13;
        state_T[(r << 4) + b] = state[i];
        z_acc[i] = bias[i >> 4];          // z_acc[r*16+b] = bias[r], coalesced
    }
    if (i < N_IN * BATCH) {
        int c = i & (N_IN - 1);
        int b = i >> 8;
        x_T[(c << 4) + b] = x[i];
    }
}

// ---------------------------------------------------------------------------
// scatter2: round-1 structure + 4-deep software pipeline.
// 16-lane group per nnz, lane = batch element; 64B-coalesced atomics.
// Non-temporal triple loads keep L2 for state_T / z_acc.
// ---------------------------------------------------------------------------
__global__ __launch_bounds__(256)
void scatter2_kernel(const float* __restrict__ vals,
                     const int* __restrict__ rows,
                     const int* __restrict__ cols,
                     const float* __restrict__ src_T,   // [n_src][16]
                     float* __restrict__ z_acc,         // [N_RES][16]
                     int nnz) {
    int tid = blockIdx.x * 256 + threadIdx.x;
    int g   = tid >> 4;
    int b   = tid & 15;
    int G   = (gridDim.x * 256) >> 4;

    int k = g;
    for (; k + 3 * G < nnz; k += 4 * G) {
        int k0 = k, k1 = k + G, k2 = k + 2 * G, k3 = k + 3 * G;
        float v0 = __builtin_nontemporal_load(vals + k0);
        float v1 = __builtin_nontemporal_load(vals + k1);
        float v2 = __builtin_nontemporal_load(vals + k2);
        float v3 = __builtin_nontemporal_load(vals + k3);
        int   r0 = __builtin_nontemporal_load(rows + k0);
        int   r1 = __builtin_nontemporal_load(rows + k1);
        int   r2 = __builtin_nontemporal_load(rows + k2);
        int   r3 = __builtin_nontemporal_load(rows + k3);
        int   c0 = __builtin_nontemporal_load(cols + k0);
        int   c1 = __builtin_nontemporal_load(cols + k1);
        int   c2 = __builtin_nontemporal_load(cols + k2);
        int   c3 = __builtin_nontemporal_load(cols + k3);
        float s0 = src_T[(c0 << 4) + b];
        float s1 = src_T[(c1 << 4) + b];
        float s2 = src_T[(c2 << 4) + b];
        float s3 = src_T[(c3 << 4) + b];
        unsafeAtomicAdd(&z_acc[(r0 << 4) + b], v0 * s0);
        unsafeAtomicAdd(&z_acc[(r1 << 4) + b], v1 * s1);
        unsafeAtomicAdd(&z_acc[(r2 << 4) + b], v2 * s2);
        unsafeAtomicAdd(&z_acc[(r3 << 4) + b], v3 * s3);
    }
    for (; k < nnz; k += G) {
        float v = vals[k];
        int   r = rows[k];
        int   c = cols[k];
        float s = src_T[(c << 4) + b];
        unsafeAtomicAdd(&z_acc[(r << 4) + b], v * s);
    }
}

// ---------------------------------------------------------------------------
// finish: out[b*N_RES + r] = erf(z_acc[r*16 + b])
// ---------------------------------------------------------------------------
__global__ void finish_kernel(const float* __restrict__ z_acc,
                              float* __restrict__ out) {
    int i = blockIdx.x * blockDim.x + threadIdx.x;
    if (i < N_RES * BATCH) {
        int b = i >> 13;
        int r = i & (N_RES - 1);
        out[i] = erff(z_acc[(r << 4) + b]);
    }
}

// ===========================================================================
// DIAGNOSTIC PROBES (results discarded; write only to scratch)
// ===========================================================================

// probeA: raw ds_add_f32 throughput, accum3-shaped addresses, no memory reads.
__global__ __launch_bounds__(512)
void probeA_lds_atomic(float* __restrict__ sink) {
    __shared__ float zl[512 * 16];                 // 32 KB
    const int tid  = threadIdx.x;
    const int lane = tid & 15;
    unsigned gid  = (unsigned)(blockIdx.x * 32 + (tid >> 4));  // group-uniform
    unsigned seed = gid * 2654435761u + 12345u;
    unsigned abase = (unsigned)(uintptr_t)&zl[lane];
    for (int i = 0; i < 256; ++i) {
        seed = seed * 1664525u + 1013904223u;
        unsigned drow = (seed >> 20) & 511u;
        asm volatile("ds_add_f32 %0, %1" : : "v"(abase + (drow << 6)), "v"(1.0f));
    }
    asm volatile("s_waitcnt lgkmcnt(0)");
    if (tid == 0) sink[blockIdx.x] = zl[0];
}

// probeB: NON-atomic LDS RMW throughput (ds_read+add+ds_write), 4 independent
// chains per iteration. Races are fine (probe only).
__global__ __launch_bounds__(512)
void probeB_lds_rmw(float* __restrict__ sink) {
    __shared__ float zl[512 * 16];                 // 32 KB
    const int tid  = threadIdx.x;
    const int lane = tid & 15;
    unsigned gid  = (unsigned)(blockIdx.x * 32 + (tid >> 4));
    unsigned seed = gid * 2654435761u + 999u;
    unsigned abase = (unsigned)(uintptr_t)&zl[lane];
    for (int i = 0; i < 256; ++i) {
        unsigned s0 = seed * 1664525u + 1013904223u;
        unsigned s1 = s0 * 1664525u + 1013904223u;
        unsigned s2 = s1 * 1664525u + 1013904223u;
        unsigned s3 = s2 * 1664525u + 1013904223u;
        seed = s3;
        unsigned a0 = abase + (((s0 >> 20) & 511u) << 6);
        unsigned a1 = abase + (((s1 >> 20) & 511u) << 6);
        unsigned a2 = abase + (((s2 >> 20) & 511u) << 6);
        unsigned a3 = abase + (((s3 >> 20) & 511u) << 6);
        float t0, t1, t2, t3;
        asm volatile("ds_read_b32 %0, %4\n\t"
                     "ds_read_b32 %1, %5\n\t"
                     "ds_read_b32 %2, %6\n\t"
                     "ds_read_b32 %3, %7\n\t"
                     "s_waitcnt lgkmcnt(0)"
                     : "=&v"(t0), "=&v"(t1), "=&v"(t2), "=&v"(t3)
                     : "v"(a0), "v"(a1), "v"(a2), "v"(a3));
        t0 += 1.0f; t1 += 1.0f; t2 += 1.0f; t3 += 1.0f;
        asm volatile("ds_write_b32 %0, %1\n\t"
                     "ds_write_b32 %2, %3\n\t"
                     "ds_write_b32 %4, %5\n\t"
                     "ds_write_b32 %6, %7"
                     : : "v"(a0), "v"(t0), "v"(a1), "v"(t1),
                         "v"(a2), "v"(t2), "v"(a3), "v"(t3));
    }
    asm volatile("s_waitcnt lgkmcnt(0)");
    if (tid == 0) sink[blockIdx.x] = zl[1];
}

// probeC: pure global-atomic issue rate — round-1 address pattern (coalesced
// 64B lines, random line), NO dependent gather. 2.1M transactions.
__global__ __launch_bounds__(256)
void probeC_glb_atomic(float* __restrict__ zc) {    // 16 MB scratch region
    int tid = blockIdx.x * 256 + threadIdx.x;
    int lane = tid & 15;
    unsigned gid = (unsigned)(tid >> 4);
    unsigned seed = (gid + 1u) * 2654435761u;
    for (int i = 0; i < 64; ++i) {
        seed = seed * 1664525u + 1013904223u;
        unsigned r = (seed >> 12) & 262143u;        // 256K lines * 64B = 16MB
        unsafeAtomicAdd(&zc[(r << 4) + lane], 1.0f);
    }
}

extern "C" void kernel_launch(void* const* d_in, const int* in_sizes, int n_in,
                              void* d_out, int out_size, void* d_ws, size_t ws_size,
                              hipStream_t stream) {
    const float* state    = (const float*)d_in[0];
    const float* x        = (const float*)d_in[1];
    const float* res_vals = (const float*)d_in[2];
    const int*   res_rows = (const int*)  d_in[3];
    const int*   res_cols = (const int*)  d_in[4];
    const float* res_bias = (const float*)d_in[5];
    const float* in_vals  = (const float*)d_in[6];
    const int*   in_rows  = (const int*)  d_in[7];
    const int*   in_cols  = (const int*)  d_in[8];
    float* out = (float*)d_out;

    float* ws      = (float*)d_ws;
    float* z_acc   = ws;                       // 131072 f (512 KB)
    float* state_T = z_acc + N_RES * BATCH;    // 131072 f (512 KB)
    float* x_T     = state_T + N_RES * BATCH;  // 4096 f (16 KB)

    int nnz_res = in_sizes[2];
    int nnz_in  = in_sizes[6];

    init_kernel<<<(N_RES * BATCH + 255) / 256, 256, 0, stream>>>(
        state, x, res_bias, z_acc, state_T, x_T);

    scatter2_kernel<<<2048, 256, 0, stream>>>(
        res_vals, res_rows, res_cols, state_T, z_acc, nnz_res);
    scatter2_kernel<<<512, 256, 0, stream>>>(
        in_vals, in_rows, in_cols, x_T, z_acc, nnz_in);

    finish_kernel<<<(N_RES * BATCH + 255) / 256, 256, 0, stream>>>(z_acc, out);

    // ---- diagnostic probes (scratch-only; after the real path) ----
    if (ws_size >= (size_t)(48u << 20)) {
        float* sink = ws + ((size_t)(6u << 20) / 4);   // @6MB
        float* zc   = ws + ((size_t)(8u << 20) / 4);   // @8MB, 16MB region
        probeA_lds_atomic<<<512, 512, 0, stream>>>(sink);
        probeB_lds_rmw  <<<512, 512, 0, stream>>>(sink + 4096);
        probeC_glb_atomic<<<2048, 256, 0, stream>>>(zc);
    }
}